// Round 9
// baseline (3065.798 us; speedup 1.0000x reference)
//
#include <hip/hip_runtime.h>

typedef unsigned short u16;
typedef unsigned long long u64;
typedef __attribute__((ext_vector_type(8))) short bf16x8;
typedef __attribute__((ext_vector_type(4))) float f32x4;

__device__ __forceinline__ float bf2f(u16 u) {
  union { unsigned int i; float f; } v; v.i = ((unsigned int)u) << 16; return v.f;
}
__device__ __forceinline__ u16 f2bf(float f) {
  union { float f; unsigned int i; } v; v.f = f;
  unsigned int r = (v.i + 0x7FFFu + ((v.i >> 16) & 1u)) >> 16;
  return (u16)r;
}
__device__ __forceinline__ float sigmoidf_(float x) { return 1.f / (1.f + __expf(-x)); }
__device__ __forceinline__ float tanhf_(float x) {
  x = fminf(fmaxf(x, -10.f), 10.f);
  float e2 = __expf(2.f * x);
  return (e2 - 1.f) / (e2 + 1.f);
}

// ---------------- workspace layout (bytes) ----------------
static const size_t OFF_GX    = 0;              // bf16 [8192][3072]
static const size_t OFF_HBUF  = 50331648;       // bf16 [2][257][32][512]
static const size_t OFF_ASRC  = 67174400;       // bf16 [8192][512]
static const size_t OFF_EW1   = 75563008;       // bf16 [8192][1024]
static const size_t OFF_B1    = 92340224;       // f32  [8192][512]
static const size_t OFF_WIHC  = 109117440;      // bf16 [3072][512]
static const size_t OFF_WWB   = 112263168;      // bf16 [512][1024]
static const size_t OFF_WO2B  = 113311744;      // bf16 [512][1024]
static const size_t OFF_WKB   = 114360320;      // bf16 [512][512]
static const size_t OFF_KWE   = 114884608;      // bf16 [512][512]
static const size_t OFF_B3    = 115408896;      // f32  [512][512]   row = b*16+t
static const size_t OFF_TP    = 116457472;      // f32  [32][512]
static const size_t OFF_TPO   = 116523008;      // f32  [32][512]
static const size_t OFF_SSUM  = 116588544;      // f32  [8192]
static const size_t OFF_BIASC = 116621312;      // f32  [3072]
static const size_t OFF_CLM   = 116633600;      // int  [8] cnt + [1] chosen

// ---------------- small prep kernels ----------------
__global__ __launch_bounds__(256) void cvtk(const float* __restrict__ s,
                                            u16* __restrict__ d, int n) {
  int i = (blockIdx.x * 256 + threadIdx.x) * 4;
  if (i < n) {
    float4 v = *(const float4*)(s + i);
    ushort4 o; o.x = f2bf(v.x); o.y = f2bf(v.y); o.z = f2bf(v.z); o.w = f2bf(v.w);
    *(ushort4*)(d + i) = o;
  }
}

// Wo2B[n][k] = Wo[n][512+k], n<512, k<1024
__global__ __launch_bounds__(256) void cvt_wo2(const float* __restrict__ Wo,
                                               u16* __restrict__ d) {
  int i = (blockIdx.x * 256 + threadIdx.x) * 4;  // over 512*1024
  int nrow = i >> 10, c = i & 1023;
  float4 v = *(const float4*)(Wo + (size_t)nrow * 1536 + 512 + c);
  ushort4 o; o.x = f2bf(v.x); o.y = f2bf(v.y); o.z = f2bf(v.z); o.w = f2bf(v.w);
  *(ushort4*)(d + i) = o;
}

// mode 0: row r uses ids[r]; mode 1 (kwemb, row=b*16+t): ids[(r&15)*32 + (r>>4)]
__global__ __launch_bounds__(256) void gather_rows(const int* __restrict__ ids,
                                                   const float* __restrict__ tab,
                                                   u16* __restrict__ dst, int mode) {
  int i = (blockIdx.x * 256 + threadIdx.x) * 8;
  int r = i >> 9, c = i & 511;
  int id = (mode == 0) ? ids[r] : ids[((r & 15) << 5) + (r >> 4)];
  const float* s = tab + (size_t)id * 512 + c;
  alignas(16) u16 o[8];
#pragma unroll
  for (int j = 0; j < 8; ++j) o[j] = f2bf(s[j]);
  *(uint4*)(dst + i) = *(const uint4*)o;
}

// tp[b][n] = bt[n] + sum_h theme_tab[theme[b]][h] * Wt[n][h]
__global__ __launch_bounds__(256) void proj_tp(const int* __restrict__ theme,
                                               const float* __restrict__ tab,
                                               const float* __restrict__ W,
                                               const float* __restrict__ bias,
                                               float* __restrict__ outp) {
  int o = blockIdx.x * 256 + threadIdx.x;  // 16384
  int b = o >> 9, n = o & 511;
  const float* emb = tab + (size_t)theme[b] * 512;
  const float* wr = W + (size_t)n * 512;
  float acc = 0.f;
  for (int h = 0; h < 512; h += 4) {
    float4 e = *(const float4*)(emb + h);
    float4 w = *(const float4*)(wr + h);
    acc += e.x * w.x + e.y * w.y + e.z * w.z + e.w * w.w;
  }
  outp[o] = acc + bias[n];
}

// tpo[b][n] = sum_h tp[b][h] * Wo[n][h]   (Wo1 = cols 0..511 of Wo rows)
__global__ __launch_bounds__(256) void proj_tpo(const float* __restrict__ tp,
                                                const float* __restrict__ Wo,
                                                float* __restrict__ outp) {
  int o = blockIdx.x * 256 + threadIdx.x;
  int b = o >> 9, n = o & 511;
  const float* emb = tp + (size_t)b * 512;
  const float* wr = Wo + (size_t)n * 1536;
  float acc = 0.f;
  for (int h = 0; h < 512; h += 4) {
    float4 e = *(const float4*)(emb + h);
    float4 w = *(const float4*)(wr + h);
    acc += e.x * w.x + e.y * w.y + e.z * w.z + e.w * w.w;
  }
  outp[o] = acc;
}

// ---------------- shared GEMM: C[M][N] = A(MxK,bf16) * B(NxK,bf16)^T ----------------
template <int EPI>
__global__ __launch_bounds__(256) void gemm_bt(const u16* __restrict__ A,
                                               const u16* __restrict__ B,
                                               const float* __restrict__ bias,
                                               float* __restrict__ Cf,
                                               u16* __restrict__ Cb, int M, int N,
                                               int K, const float* __restrict__ ssum,
                                               const float* __restrict__ tpo) {
  __shared__ u16 As[128][72];
  __shared__ u16 Bs[128][72];
  const int tid = threadIdx.x;
  const int mtiles = M >> 7;
  const int mt = blockIdx.x % mtiles, nt = blockIdx.x / mtiles;
  const int wave = tid >> 6, lane = tid & 63;
  const int wr = wave >> 1, wc = wave & 1;
  const int l16 = lane & 15, l4 = lane >> 4;
  f32x4 acc[4][4] = {};
  const int nkt = K >> 6;
  for (int kt = 0; kt < nkt; ++kt) {
    __syncthreads();
#pragma unroll
    for (int i = 0; i < 4; ++i) {
      int c = i * 256 + tid;
      int row = c >> 3, c8 = c & 7;
      uint4 va = *(const uint4*)(A + (size_t)(mt * 128 + row) * K + kt * 64 + c8 * 8);
      *(uint4*)&As[row][c8 * 8] = va;
      uint4 vb = *(const uint4*)(B + (size_t)(nt * 128 + row) * K + kt * 64 + c8 * 8);
      *(uint4*)&Bs[row][c8 * 8] = vb;
    }
    __syncthreads();
#pragma unroll
    for (int kk = 0; kk < 2; ++kk) {
      bf16x8 af[4], bfr[4];
#pragma unroll
      for (int m = 0; m < 4; ++m)
        af[m] = *(const bf16x8*)&As[wr * 64 + m * 16 + l16][kk * 32 + l4 * 8];
#pragma unroll
      for (int n = 0; n < 4; ++n)
        bfr[n] = *(const bf16x8*)&Bs[wc * 64 + n * 16 + l16][kk * 32 + l4 * 8];
#pragma unroll
      for (int m = 0; m < 4; ++m)
#pragma unroll
        for (int n = 0; n < 4; ++n)
          acc[m][n] = __builtin_amdgcn_mfma_f32_16x16x32_bf16(af[m], bfr[n],
                                                              acc[m][n], 0, 0, 0);
    }
  }
#pragma unroll
  for (int m = 0; m < 4; ++m) {
    int rg = mt * 128 + wr * 64 + m * 16 + l4 * 4;
#pragma unroll
    for (int n = 0; n < 4; ++n) {
      int cg = nt * 128 + wc * 64 + n * 16 + l16;
      float bb = bias[cg];
#pragma unroll
      for (int i = 0; i < 4; ++i) {
        int r = rg + i;
        float v = acc[m][n][i] + bb;
        if (EPI == 2) v += ssum[r] * tpo[(r & 31) * 512 + cg];
        if (EPI == 0) Cb[(size_t)r * N + cg] = f2bf(v);
        else Cf[(size_t)r * N + cg] = v;
      }
    }
  }
}

// ---------------- GRU scan v9: sentinel-in-data protocol (v8 + stride fix) ----------
// hbuf pre-filled with 0xFF (dword 0xFFFFFFFF = bf16 NaN pair, unreachable).
// Consumers poll their OWN A-fragments with relaxed agent u64 atomic loads until
// no dword is sentinel -> the polled values ARE the MFMA operands.
// Producers: gates -> packed dword agent atomic stores. No drain/flag/end barrier.
// One __syncthreads per step (pbuf, parity double-buffered).
__global__ __launch_bounds__(512, 1) void gru_scan(
    const u16* __restrict__ gx,      // [8192][3072]
    const float* __restrict__ Whh_f, const float* __restrict__ Whh_b,
    const float* __restrict__ bhh_f, const float* __restrict__ bhh_b,
    u16* __restrict__ hbuf,          // [2][257][32][512]
    int* __restrict__ clm)           // [8] per-XCD count, [8] = chosen+1
{
  __shared__ float pbuf[2][4][3][4][64];
  __shared__ int sInfo[2];
  const int tid = threadIdx.x;

  int xcc;
  asm volatile("s_getreg_b32 %0, hwreg(HW_REG_XCC_ID)" : "=s"(xcc));
  xcc &= 7;
  if (tid == 0) {
    int r = __hip_atomic_fetch_add(&clm[xcc], 1, __ATOMIC_RELAXED,
                                   __HIP_MEMORY_SCOPE_AGENT);
    sInfo[0] = r;
    if (r == 31) {
      int exp = 0;
      __hip_atomic_compare_exchange_strong(&clm[8], &exp, xcc + 1,
                                           __ATOMIC_RELAXED, __ATOMIC_RELAXED,
                                           __HIP_MEMORY_SCOPE_AGENT);
    }
    int c;
    do {
      c = __hip_atomic_load(&clm[8], __ATOMIC_RELAXED, __HIP_MEMORY_SCOPE_AGENT);
      if (c == 0) __builtin_amdgcn_s_sleep(8);
    } while (c == 0);
    sInfo[1] = c - 1;
  }
  __syncthreads();
  const int rank = sInfo[0];
  if (sInfo[1] != xcc || rank >= 32) return;

  const int d = rank & 1;           // direction
  const int slice = rank >> 1;      // 16 col-slices of 32
  const float* Whh = d ? Whh_b : Whh_f;
  const float* bhh = d ? bhh_b : bhh_f;

  const int wave = tid >> 6, lane = tid & 63;
  const int kh = wave >> 2, m = (wave >> 1) & 1, a = wave & 1;
  const int p = m * 2 + a;
  const int l16 = lane & 15, l4 = lane >> 4;
  const int j = a * 16 + l16;       // col within slice (0..31)

  // ---- preload Whh B-fragments into registers: wfrag[gate][kk] ----
  bf16x8 wfrag[3][8];
#pragma unroll
  for (int g = 0; g < 3; ++g) {
    const float* wrow = Whh + (size_t)(g * 512 + slice * 32 + j) * 512;
#pragma unroll
    for (int kk = 0; kk < 8; ++kk) {
      const float* wp = wrow + (kh * 8 + kk) * 32 + l4 * 8;
      float4 v0 = *(const float4*)wp;
      float4 v1 = *(const float4*)(wp + 4);
      alignas(16) u16 tmp[8];
      tmp[0] = f2bf(v0.x); tmp[1] = f2bf(v0.y); tmp[2] = f2bf(v0.z); tmp[3] = f2bf(v0.w);
      tmp[4] = f2bf(v1.x); tmp[5] = f2bf(v1.y); tmp[6] = f2bf(v1.z); tmp[7] = f2bf(v1.w);
      wfrag[g][kk] = *(const bf16x8*)tmp;
    }
  }
  float bR = 0.f, bZ = 0.f, bN = 0.f;
  if (kh == 0) {
    bR = bhh[slice * 32 + j];
    bZ = bhh[512 + slice * 32 + j];
    bN = bhh[1024 + slice * 32 + j];
  }
  float hreg[4] = {0.f, 0.f, 0.f, 0.f};

  const size_t dbase = (size_t)d * 257 * 32 * 512;

  for (int t = 0; t < 256; ++t) {
    // issue gx loads (raw u16) for this step before polling: HBM latency
    // overlaps the producer wait; consumed (converted) only in the gate phase.
    u16 xgu[3][4];
    if (kh == 0) {
      int trow = d ? (255 - t) : t;
      const u16* gb = gx + (size_t)(trow * 32 + m * 16 + l4 * 4) * 3072 +
                      d * 1536 + slice * 32 + j;
#pragma unroll
      for (int i = 0; i < 4; ++i)
#pragma unroll
        for (int g = 0; g < 3; ++g)
          xgu[g][i] = gb[(size_t)i * 3072 + g * 512];
      __builtin_amdgcn_sched_barrier(0);
    }

    // ---- poll + load own A fragments (sentinel protocol) ----
    // fragment: 8 chunks of 16B; chunk kk at element offset kk*32 (u16)
    //           = kk*8 in u64 units. (v8 bug: used kk*4 -> wrong operands.)
    u64 a8[16];
    {
      const u64* hp = (const u64*)(hbuf + dbase + (size_t)t * 32 * 512 +
                                   (size_t)(m * 16 + l16) * 512 + kh * 256 +
                                   l4 * 8);
      int spins = 0;
      while (true) {
        bool ok = true;
#pragma unroll
        for (int kk = 0; kk < 8; ++kk) {
          a8[2 * kk] = __hip_atomic_load(hp + (size_t)kk * 8, __ATOMIC_RELAXED,
                                         __HIP_MEMORY_SCOPE_AGENT);
          a8[2 * kk + 1] = __hip_atomic_load(hp + (size_t)kk * 8 + 1,
                                             __ATOMIC_RELAXED,
                                             __HIP_MEMORY_SCOPE_AGENT);
        }
#pragma unroll
        for (int q = 0; q < 16; ++q) {
          ok &= ((unsigned int)a8[q] != 0xFFFFFFFFu);
          ok &= ((unsigned int)(a8[q] >> 32) != 0xFFFFFFFFu);
        }
        if (__all(ok)) break;
        if (++spins > 65536) break;  // safety: fail fast instead of hanging
      }
    }

    f32x4 acc[3] = {};
#pragma unroll
    for (int kk = 0; kk < 8; ++kk) {
      union { u64 u[2]; bf16x8 v; } cv;
      cv.u[0] = a8[2 * kk]; cv.u[1] = a8[2 * kk + 1];
#pragma unroll
      for (int g = 0; g < 3; ++g)
        acc[g] = __builtin_amdgcn_mfma_f32_16x16x32_bf16(cv.v, wfrag[g][kk],
                                                         acc[g], 0, 0, 0);
    }

    if (kh == 1) {
#pragma unroll
      for (int g = 0; g < 3; ++g)
#pragma unroll
        for (int i = 0; i < 4; ++i) pbuf[t & 1][p][g][i][lane] = acc[g][i];
    }
    __syncthreads();

    if (kh == 0) {
      u16* hrow = hbuf + dbase + (size_t)(t + 1) * 32 * 512 + slice * 32;
#pragma unroll
      for (int i = 0; i < 4; ++i) {
        float hr = acc[0][i] + pbuf[t & 1][p][0][i][lane] + bR;
        float hz = acc[1][i] + pbuf[t & 1][p][1][i][lane] + bZ;
        float hn = acc[2][i] + pbuf[t & 1][p][2][i][lane] + bN;
        float rr = sigmoidf_(bf2f(xgu[0][i]) + hr);
        float zz = sigmoidf_(bf2f(xgu[1][i]) + hz);
        float nn = tanhf_(bf2f(xgu[2][i]) + rr * hn);
        hreg[i] = (1.f - zz) * nn + zz * hreg[i];
      }
      // pack lane pairs -> native dword agent stores (write to LLC, no drain)
#pragma unroll
      for (int i = 0; i < 4; ++i) {
        unsigned int myb = f2bf(hreg[i]);
        unsigned int ob = (unsigned int)__shfl_xor((int)myb, 1);
        if ((l16 & 1) == 0) {
          unsigned int w = (myb & 0xffffu) | (ob << 16);
          unsigned int* dst = (unsigned int*)(hrow +
                              (size_t)(m * 16 + l4 * 4 + i) * 512 + j);
          __hip_atomic_store(dst, w, __ATOMIC_RELAXED, __HIP_MEMORY_SCOPE_AGENT);
        }
      }
    }
  }
}

// enc_w1[r][0:512] = ys_f[s][b] = hbuf[0][s+1][b]; [512:1024] = ys_b[s][b] = hbuf[1][256-s][b]
__global__ __launch_bounds__(256) void build_encw1(const u16* __restrict__ hbuf,
                                                   u16* __restrict__ ew) {
  int idx = (blockIdx.x * 256 + threadIdx.x) * 8;
  int r = idx >> 10, c = idx & 1023;
  int s = r >> 5, b = r & 31;
  size_t src;
  if (c < 512) src = ((size_t)(s + 1) * 32 + b) * 512 + c;
  else src = ((size_t)(257 + 256 - s) * 32 + b) * 512 + (c - 512);
  *(uint4*)(ew + idx) = *(const uint4*)(hbuf + src);
}

// ssum[r] = sum_t sum_h wv[h]*tanh(b1[r][h] + tp[b][h] + b3[b*16+t][h]) + 16*bv
__global__ __launch_bounds__(256) void scores_k(const float* __restrict__ b1,
                                                const float* __restrict__ tp,
                                                const float* __restrict__ b3,
                                                const float* __restrict__ wv,
                                                const float* __restrict__ bv,
                                                float* __restrict__ ssum) {
  __shared__ float pre[512];
  __shared__ float wvs[512];
  __shared__ float red[4];
  int r = blockIdx.x;
  int tid = threadIdx.x;
  int b = r & 31;
  for (int h = tid; h < 512; h += 256) {
    pre[h] = b1[(size_t)r * 512 + h] + tp[b * 512 + h];
    wvs[h] = wv[h];
  }
  __syncthreads();
  float acc = 0.f;
  for (int t = 0; t < 16; ++t) {
    const float* b3r = b3 + ((size_t)b * 16 + t) * 512;
    for (int h = tid; h < 512; h += 256) acc += wvs[h] * tanhf_(pre[h] + b3r[h]);
  }
  for (int o = 32; o > 0; o >>= 1) acc += __shfl_down(acc, o);
  if ((tid & 63) == 0) red[tid >> 6] = acc;
  __syncthreads();
  if (tid == 0) ssum[r] = red[0] + red[1] + red[2] + red[3] + 16.f * bv[0];
}

// enc_hidden_out[b][n] = sum_k [hT_f|hT_b][b][k] * Who[n][k]
__global__ __launch_bounds__(256) void hidden_k(const u16* __restrict__ hbuf,
                                                const float* __restrict__ Who,
                                                float* __restrict__ outp) {
  int o = blockIdx.x * 256 + threadIdx.x;  // 16384
  int b = o >> 9, n = o & 511;
  const u16* hf = hbuf + ((size_t)256 * 32 + b) * 512;
  const u16* hb = hbuf + ((size_t)(257 + 256) * 32 + b) * 512;
  const float* w = Who + (size_t)n * 1024;
  float acc = 0.f;
  for (int k = 0; k < 512; ++k) acc += bf2f(hf[k]) * w[k];
  for (int k = 0; k < 512; ++k) acc += bf2f(hb[k]) * w[512 + k];
  outp[o] = acc;
}

extern "C" void kernel_launch(void* const* d_in, const int* in_sizes, int n_in,
                              void* d_out, int out_size, void* d_ws, size_t ws_size,
                              hipStream_t stream) {
  (void)in_sizes; (void)n_in; (void)out_size; (void)ws_size;
  const int* theme = (const int*)d_in[0];
  const int* keyword = (const int*)d_in[1];
  const int* src = (const int*)d_in[2];
  const float* theme_tab = (const float*)d_in[3];
  const float* keyword_tab = (const float*)d_in[4];
  const float* src_tab = (const float*)d_in[5];
  const float* Wih_f = (const float*)d_in[6];
  const float* Whh_f = (const float*)d_in[7];
  const float* bih_f = (const float*)d_in[8];
  const float* bhh_f = (const float*)d_in[9];
  const float* Wih_b = (const float*)d_in[10];
  const float* Whh_b = (const float*)d_in[11];
  const float* bih_b = (const float*)d_in[12];
  const float* bhh_b = (const float*)d_in[13];
  const float* Ww = (const float*)d_in[14];
  const float* bw = (const float*)d_in[15];
  const float* Wt = (const float*)d_in[16];
  const float* bt = (const float*)d_in[17];
  const float* Wk = (const float*)d_in[18];
  const float* bk = (const float*)d_in[19];
  const float* wv = (const float*)d_in[20];
  const float* bv = (const float*)d_in[21];
  const float* Wo = (const float*)d_in[22];
  const float* bo = (const float*)d_in[23];
  const float* Who = (const float*)d_in[24];
  float* out = (float*)d_out;
  char* ws = (char*)d_ws;

  u16* gx_cat = (u16*)(ws + OFF_GX);
  u16* hbuf = (u16*)(ws + OFF_HBUF);
  u16* asrc = (u16*)(ws + OFF_ASRC);
  u16* ew1 = (u16*)(ws + OFF_EW1);
  float* b1buf = (float*)(ws + OFF_B1);
  u16* wihc = (u16*)(ws + OFF_WIHC);
  u16* wwb = (u16*)(ws + OFF_WWB);
  u16* wo2b = (u16*)(ws + OFF_WO2B);
  u16* wkb = (u16*)(ws + OFF_WKB);
  u16* kwe = (u16*)(ws + OFF_KWE);
  float* b3buf = (float*)(ws + OFF_B3);
  float* tp = (float*)(ws + OFF_TP);
  float* tpo = (float*)(ws + OFF_TPO);
  float* ssum = (float*)(ws + OFF_SSUM);
  float* biasc = (float*)(ws + OFF_BIASC);
  int* clm = (int*)(ws + OFF_CLM);

  // init: sentinel-fill the whole h ring (0xFFFFFFFF dwords = bf16-NaN pairs),
  // then zero the two t=0 planes; claim counters zeroed.
  hipMemsetAsync(hbuf, 0xFF, (size_t)2 * 257 * 32 * 512 * 2, stream);
  hipMemsetAsync(hbuf, 0, 32 * 512 * 2, stream);
  hipMemsetAsync(hbuf + (size_t)257 * 32 * 512, 0, 32 * 512 * 2, stream);
  hipMemsetAsync(clm, 0, 64, stream);
  // bias_cat = [bih_f, bih_b]
  hipMemcpyAsync(biasc, bih_f, 1536 * 4, hipMemcpyDeviceToDevice, stream);
  hipMemcpyAsync(biasc + 1536, bih_b, 1536 * 4, hipMemcpyDeviceToDevice, stream);

  // weight conversions
  cvtk<<<768, 256, 0, stream>>>(Wih_f, wihc, 1536 * 512);
  cvtk<<<768, 256, 0, stream>>>(Wih_b, wihc + 1536 * 512, 1536 * 512);
  cvtk<<<512, 256, 0, stream>>>(Ww, wwb, 512 * 1024);
  cvtk<<<256, 256, 0, stream>>>(Wk, wkb, 512 * 512);
  cvt_wo2<<<512, 256, 0, stream>>>(Wo, wo2b);
  // gathers
  gather_rows<<<2048, 256, 0, stream>>>(src, src_tab, asrc, 0);
  gather_rows<<<128, 256, 0, stream>>>(keyword, keyword_tab, kwe, 1);
  // small projections
  proj_tp<<<64, 256, 0, stream>>>(theme, theme_tab, Wt, bt, tp);
  proj_tpo<<<64, 256, 0, stream>>>(tp, Wo, tpo);
  // b3 = kwemb @ Wk^T + bk   (M=512,N=512,K=512)
  gemm_bt<1><<<16, 256, 0, stream>>>(kwe, wkb, bk, b3buf, nullptr, 512, 512, 512,
                                     nullptr, nullptr);
  // gx = src_emb @ [Wih_f;Wih_b]^T + bih  (M=8192,N=3072,K=512) -> bf16
  gemm_bt<0><<<1536, 256, 0, stream>>>(asrc, wihc, biasc, nullptr, gx_cat, 8192,
                                       3072, 512, nullptr, nullptr);
  // sequential bidirectional GRU — one XCD claim + sentinel data-poll protocol
  gru_scan<<<256, 512, 0, stream>>>(gx_cat, Whh_f, Whh_b, bhh_f, bhh_b, hbuf, clm);
  // enc_w_1 materialization
  build_encw1<<<4096, 256, 0, stream>>>(hbuf, ew1);
  // b1 = enc_w_1 @ Ww^T + bw  (M=8192,N=512,K=1024) -> f32
  gemm_bt<1><<<256, 256, 0, stream>>>(ew1, wwb, bw, b1buf, nullptr, 8192, 512, 1024,
                                      nullptr, nullptr);
  // attention scalar per (s,b)
  scores_k<<<8192, 256, 0, stream>>>(b1buf, tp, b3buf, wv, bv, ssum);
  // enc_out = enc_w1 @ Wo2^T + bo + ssum*tpo  -> d_out (f32)
  gemm_bt<2><<<256, 256, 0, stream>>>(ew1, wo2b, bo, out, nullptr, 8192, 512, 1024,
                                      ssum, tpo);
  // enc_hidden_out
  hidden_k<<<64, 256, 0, stream>>>(hbuf, Who, out + 4194304);
}

// Round 10
// 1293.418 us; speedup vs baseline: 2.3703x; 2.3703x over previous
//
#include <hip/hip_runtime.h>

typedef unsigned short u16;
typedef unsigned long long u64;
typedef __attribute__((ext_vector_type(8))) short bf16x8;
typedef __attribute__((ext_vector_type(4))) float f32x4;

__device__ __forceinline__ float bf2f(u16 u) {
  union { unsigned int i; float f; } v; v.i = ((unsigned int)u) << 16; return v.f;
}
__device__ __forceinline__ u16 f2bf(float f) {
  union { float f; unsigned int i; } v; v.f = f;
  unsigned int r = (v.i + 0x7FFFu + ((v.i >> 16) & 1u)) >> 16;
  return (u16)r;
}
__device__ __forceinline__ float sigmoidf_(float x) { return 1.f / (1.f + __expf(-x)); }
__device__ __forceinline__ float tanhf_(float x) {
  x = fminf(fmaxf(x, -10.f), 10.f);
  float e2 = __expf(2.f * x);
  return (e2 - 1.f) / (e2 + 1.f);
}

// ---------------- workspace layout (bytes) ----------------
static const size_t OFF_GX    = 0;              // bf16 [8192][3072]
static const size_t OFF_HBUF  = 50331648;       // bf16 [2][257][32][512]
static const size_t OFF_ASRC  = 67174400;       // bf16 [8192][512]
static const size_t OFF_EW1   = 75563008;       // bf16 [8192][1024]
static const size_t OFF_B1    = 92340224;       // f32  [8192][512]
static const size_t OFF_WIHC  = 109117440;      // bf16 [3072][512]
static const size_t OFF_WWB   = 112263168;      // bf16 [512][1024]
static const size_t OFF_WO2B  = 113311744;      // bf16 [512][1024]
static const size_t OFF_WKB   = 114360320;      // bf16 [512][512]
static const size_t OFF_KWE   = 114884608;      // bf16 [512][512]
static const size_t OFF_B3    = 115408896;      // f32  [512][512]   row = b*16+t
static const size_t OFF_TP    = 116457472;      // f32  [32][512]
static const size_t OFF_TPO   = 116523008;      // f32  [32][512]
static const size_t OFF_SSUM  = 116588544;      // f32  [8192]
static const size_t OFF_BIASC = 116621312;      // f32  [3072]
static const size_t OFF_FLG   = 116633600;      // int; one 64B line per [2][257][16]
static const size_t OFF_CLM   = OFF_FLG + 526336;  // int [16]

// ---------------- small prep kernels ----------------
__global__ __launch_bounds__(256) void cvtk(const float* __restrict__ s,
                                            u16* __restrict__ d, int n) {
  int i = (blockIdx.x * 256 + threadIdx.x) * 4;
  if (i < n) {
    float4 v = *(const float4*)(s + i);
    ushort4 o; o.x = f2bf(v.x); o.y = f2bf(v.y); o.z = f2bf(v.z); o.w = f2bf(v.w);
    *(ushort4*)(d + i) = o;
  }
}

// Wo2B[n][k] = Wo[n][512+k], n<512, k<1024
__global__ __launch_bounds__(256) void cvt_wo2(const float* __restrict__ Wo,
                                               u16* __restrict__ d) {
  int i = (blockIdx.x * 256 + threadIdx.x) * 4;  // over 512*1024
  int nrow = i >> 10, c = i & 1023;
  float4 v = *(const float4*)(Wo + (size_t)nrow * 1536 + 512 + c);
  ushort4 o; o.x = f2bf(v.x); o.y = f2bf(v.y); o.z = f2bf(v.z); o.w = f2bf(v.w);
  *(ushort4*)(d + i) = o;
}

// mode 0: row r uses ids[r]; mode 1 (kwemb, row=b*16+t): ids[(r&15)*32 + (r>>4)]
__global__ __launch_bounds__(256) void gather_rows(const int* __restrict__ ids,
                                                   const float* __restrict__ tab,
                                                   u16* __restrict__ dst, int mode) {
  int i = (blockIdx.x * 256 + threadIdx.x) * 8;
  int r = i >> 9, c = i & 511;
  int id = (mode == 0) ? ids[r] : ids[((r & 15) << 5) + (r >> 4)];
  const float* s = tab + (size_t)id * 512 + c;
  alignas(16) u16 o[8];
#pragma unroll
  for (int j = 0; j < 8; ++j) o[j] = f2bf(s[j]);
  *(uint4*)(dst + i) = *(const uint4*)o;
}

// tp[b][n] = bt[n] + sum_h theme_tab[theme[b]][h] * Wt[n][h]
__global__ __launch_bounds__(256) void proj_tp(const int* __restrict__ theme,
                                               const float* __restrict__ tab,
                                               const float* __restrict__ W,
                                               const float* __restrict__ bias,
                                               float* __restrict__ outp) {
  int o = blockIdx.x * 256 + threadIdx.x;  // 16384
  int b = o >> 9, n = o & 511;
  const float* emb = tab + (size_t)theme[b] * 512;
  const float* wr = W + (size_t)n * 512;
  float acc = 0.f;
  for (int h = 0; h < 512; h += 4) {
    float4 e = *(const float4*)(emb + h);
    float4 w = *(const float4*)(wr + h);
    acc += e.x * w.x + e.y * w.y + e.z * w.z + e.w * w.w;
  }
  outp[o] = acc + bias[n];
}

// tpo[b][n] = sum_h tp[b][h] * Wo[n][h]   (Wo1 = cols 0..511 of Wo rows)
__global__ __launch_bounds__(256) void proj_tpo(const float* __restrict__ tp,
                                                const float* __restrict__ Wo,
                                                float* __restrict__ outp) {
  int o = blockIdx.x * 256 + threadIdx.x;
  int b = o >> 9, n = o & 511;
  const float* emb = tp + (size_t)b * 512;
  const float* wr = Wo + (size_t)n * 1536;
  float acc = 0.f;
  for (int h = 0; h < 512; h += 4) {
    float4 e = *(const float4*)(emb + h);
    float4 w = *(const float4*)(wr + h);
    acc += e.x * w.x + e.y * w.y + e.z * w.z + e.w * w.w;
  }
  outp[o] = acc;
}

// ---------------- shared GEMM: C[M][N] = A(MxK,bf16) * B(NxK,bf16)^T ----------------
template <int EPI>
__global__ __launch_bounds__(256) void gemm_bt(const u16* __restrict__ A,
                                               const u16* __restrict__ B,
                                               const float* __restrict__ bias,
                                               float* __restrict__ Cf,
                                               u16* __restrict__ Cb, int M, int N,
                                               int K, const float* __restrict__ ssum,
                                               const float* __restrict__ tpo) {
  __shared__ u16 As[128][72];
  __shared__ u16 Bs[128][72];
  const int tid = threadIdx.x;
  const int mtiles = M >> 7;
  const int mt = blockIdx.x % mtiles, nt = blockIdx.x / mtiles;
  const int wave = tid >> 6, lane = tid & 63;
  const int wr = wave >> 1, wc = wave & 1;
  const int l16 = lane & 15, l4 = lane >> 4;
  f32x4 acc[4][4] = {};
  const int nkt = K >> 6;
  for (int kt = 0; kt < nkt; ++kt) {
    __syncthreads();
#pragma unroll
    for (int i = 0; i < 4; ++i) {
      int c = i * 256 + tid;
      int row = c >> 3, c8 = c & 7;
      uint4 va = *(const uint4*)(A + (size_t)(mt * 128 + row) * K + kt * 64 + c8 * 8);
      *(uint4*)&As[row][c8 * 8] = va;
      uint4 vb = *(const uint4*)(B + (size_t)(nt * 128 + row) * K + kt * 64 + c8 * 8);
      *(uint4*)&Bs[row][c8 * 8] = vb;
    }
    __syncthreads();
#pragma unroll
    for (int kk = 0; kk < 2; ++kk) {
      bf16x8 af[4], bfr[4];
#pragma unroll
      for (int m = 0; m < 4; ++m)
        af[m] = *(const bf16x8*)&As[wr * 64 + m * 16 + l16][kk * 32 + l4 * 8];
#pragma unroll
      for (int n = 0; n < 4; ++n)
        bfr[n] = *(const bf16x8*)&Bs[wc * 64 + n * 16 + l16][kk * 32 + l4 * 8];
#pragma unroll
      for (int m = 0; m < 4; ++m)
#pragma unroll
        for (int n = 0; n < 4; ++n)
          acc[m][n] = __builtin_amdgcn_mfma_f32_16x16x32_bf16(af[m], bfr[n],
                                                              acc[m][n], 0, 0, 0);
    }
  }
#pragma unroll
  for (int m = 0; m < 4; ++m) {
    int rg = mt * 128 + wr * 64 + m * 16 + l4 * 4;
#pragma unroll
    for (int n = 0; n < 4; ++n) {
      int cg = nt * 128 + wc * 64 + n * 16 + l16;
      float bb = bias[cg];
#pragma unroll
      for (int i = 0; i < 4; ++i) {
        int r = rg + i;
        float v = acc[m][n][i] + bb;
        if (EPI == 2) v += ssum[r] * tpo[(r & 31) * 512 + cg];
        if (EPI == 0) Cb[(size_t)r * N + cg] = f2bf(v);
        else Cf[(size_t)r * N + cg] = v;
      }
    }
  }
}

// ---------------- GRU scan v10: v5 + flag-line spreading + non-gx poller ----------
// v5 protocol (proven): relaxed agent atomic stores -> vmcnt(0) -> barrier ->
// relaxed flag store; consumer: relaxed flag poll -> workgroup acquire -> plain loads.
// v10 changes: (1) each flag gets its OWN 64B line -> producers never share a
// line, 16 pollers/line instead of 256+; (2) poller is wave 4 (kh=1, no gx
// loads) so poll vmcnt never drains HBM traffic.
__global__ __launch_bounds__(512, 1) void gru_scan(
    const u16* __restrict__ gx,      // [8192][3072]
    const float* __restrict__ Whh_f, const float* __restrict__ Whh_b,
    const float* __restrict__ bhh_f, const float* __restrict__ bhh_b,
    u16* __restrict__ hbuf,          // [2][257][32][512]
    int* __restrict__ flg,           // one 64B line per [2][257][16]
    int* __restrict__ clm)           // [8] per-XCD count, [8] = chosen+1
{
  __shared__ float pbuf[4][3][4][64];
  __shared__ int sInfo[2];
  const int tid = threadIdx.x;

  int xcc;
  asm volatile("s_getreg_b32 %0, hwreg(HW_REG_XCC_ID)" : "=s"(xcc));
  xcc &= 7;
  if (tid == 0) {
    int r = __hip_atomic_fetch_add(&clm[xcc], 1, __ATOMIC_RELAXED,
                                   __HIP_MEMORY_SCOPE_AGENT);
    sInfo[0] = r;
    if (r == 31) {
      int exp = 0;
      __hip_atomic_compare_exchange_strong(&clm[8], &exp, xcc + 1,
                                           __ATOMIC_RELAXED, __ATOMIC_RELAXED,
                                           __HIP_MEMORY_SCOPE_AGENT);
    }
    int c;
    do {
      c = __hip_atomic_load(&clm[8], __ATOMIC_RELAXED, __HIP_MEMORY_SCOPE_AGENT);
      if (c == 0) __builtin_amdgcn_s_sleep(8);
    } while (c == 0);
    sInfo[1] = c - 1;
  }
  __syncthreads();
  const int rank = sInfo[0];
  if (sInfo[1] != xcc || rank >= 32) return;

  const int d = rank & 1;           // direction
  const int slice = rank >> 1;      // 16 col-slices of 32
  const float* Whh = d ? Whh_b : Whh_f;
  const float* bhh = d ? bhh_b : bhh_f;

  const int wave = tid >> 6, lane = tid & 63;
  const int kh = wave >> 2, m = (wave >> 1) & 1, a = wave & 1;
  const int p = m * 2 + a;
  const int l16 = lane & 15, l4 = lane >> 4;
  const int j = a * 16 + l16;       // col within slice (0..31)

  // ---- preload Whh B-fragments into registers: wfrag[gate][kk] ----
  bf16x8 wfrag[3][8];
#pragma unroll
  for (int g = 0; g < 3; ++g) {
    const float* wrow = Whh + (size_t)(g * 512 + slice * 32 + j) * 512;
#pragma unroll
    for (int kk = 0; kk < 8; ++kk) {
      const float* wp = wrow + (kh * 8 + kk) * 32 + l4 * 8;
      float4 v0 = *(const float4*)wp;
      float4 v1 = *(const float4*)(wp + 4);
      alignas(16) u16 tmp[8];
      tmp[0] = f2bf(v0.x); tmp[1] = f2bf(v0.y); tmp[2] = f2bf(v0.z); tmp[3] = f2bf(v0.w);
      tmp[4] = f2bf(v1.x); tmp[5] = f2bf(v1.y); tmp[6] = f2bf(v1.z); tmp[7] = f2bf(v1.w);
      wfrag[g][kk] = *(const bf16x8*)tmp;
    }
  }
  float bR = 0.f, bZ = 0.f, bN = 0.f;
  if (kh == 0) {
    bR = bhh[slice * 32 + j];
    bZ = bhh[512 + slice * 32 + j];
    bN = bhh[1024 + slice * 32 + j];
  }
  float hreg[4] = {0.f, 0.f, 0.f, 0.f};

  const size_t dbase = (size_t)d * 257 * 32 * 512;
  int* const flgd = flg + (size_t)d * 257 * 16 * 16;   // 16 ints (64B) per flag

  for (int t = 0; t < 256; ++t) {
    // prefetch gx for this step (kh=0 waves; consumed in gate phase)
    float xg[3][4];
    if (kh == 0) {
      int trow = d ? (255 - t) : t;
      const u16* gb = gx + (size_t)(trow * 32 + m * 16 + l4 * 4) * 3072 +
                      d * 1536 + slice * 32 + j;
#pragma unroll
      for (int i = 0; i < 4; ++i)
#pragma unroll
        for (int g = 0; g < 3; ++g)
          xg[g][i] = bf2f(gb[(size_t)i * 3072 + g * 512]);
      __builtin_amdgcn_sched_barrier(0);
    }

    if (t > 0) {
      if (wave == 4) {   // kh=1 wave: no gx loads queued ahead of poll
        const int* fp = flgd + ((size_t)t * 16 + l16) * 16;
        while (true) {
          int v = __hip_atomic_load(fp, __ATOMIC_RELAXED, __HIP_MEMORY_SCOPE_AGENT);
          if (__all(v != 0)) break;
        }
      }
      __builtin_amdgcn_fence(__ATOMIC_ACQUIRE, "workgroup");
      __syncthreads();
    }

    // ---- A-fragment loads: plain vector loads (fresh addresses every step) ----
    const u16* hsrc = hbuf + dbase + (size_t)t * 32 * 512 +
                      (size_t)(m * 16 + l16) * 512 + kh * 256 + l4 * 8;
    uint4 areg[8];
#pragma unroll
    for (int kk = 0; kk < 8; ++kk)
      areg[kk] = *(const uint4*)(hsrc + kk * 32);

    f32x4 acc[3] = {};
#pragma unroll
    for (int kk = 0; kk < 8; ++kk) {
      union { uint4 u; bf16x8 v; } cv;
      cv.u = areg[kk];
#pragma unroll
      for (int g = 0; g < 3; ++g)
        acc[g] = __builtin_amdgcn_mfma_f32_16x16x32_bf16(cv.v, wfrag[g][kk],
                                                         acc[g], 0, 0, 0);
    }

    if (kh == 1) {
#pragma unroll
      for (int g = 0; g < 3; ++g)
#pragma unroll
        for (int i = 0; i < 4; ++i) pbuf[p][g][i][lane] = acc[g][i];
    }
    __syncthreads();

    if (kh == 0) {
      u16* hrow = hbuf + dbase + (size_t)(t + 1) * 32 * 512 + slice * 32;
#pragma unroll
      for (int i = 0; i < 4; ++i) {
        float hr = acc[0][i] + pbuf[p][0][i][lane] + bR;
        float hz = acc[1][i] + pbuf[p][1][i][lane] + bZ;
        float hn = acc[2][i] + pbuf[p][2][i][lane] + bN;
        float rr = sigmoidf_(xg[0][i] + hr);
        float zz = sigmoidf_(xg[1][i] + hz);
        float nn = tanhf_(xg[2][i] + rr * hn);
        hreg[i] = (1.f - zz) * nn + zz * hreg[i];
      }
      // pack lane pairs -> native dword stores (agent scope, land at LLC)
#pragma unroll
      for (int i = 0; i < 4; ++i) {
        unsigned int myb = f2bf(hreg[i]);
        unsigned int ob = (unsigned int)__shfl_xor((int)myb, 1);
        if ((l16 & 1) == 0) {
          unsigned int w = (myb & 0xffffu) | (ob << 16);
          unsigned int* dst = (unsigned int*)(hrow +
                              (size_t)(m * 16 + l4 * 4 + i) * 512 + j);
          __hip_atomic_store(dst, w, __ATOMIC_RELAXED, __HIP_MEMORY_SCOPE_AGENT);
        }
      }
    }
    // drain this wave's stores, then signal via own 64B flag line
    asm volatile("s_waitcnt vmcnt(0)" ::: "memory");
    __syncthreads();
    if (tid == 0)
      __hip_atomic_store(flgd + ((size_t)(t + 1) * 16 + slice) * 16, 1,
                         __ATOMIC_RELAXED, __HIP_MEMORY_SCOPE_AGENT);
  }
}

// enc_w1[r][0:512] = ys_f[s][b] = hbuf[0][s+1][b]; [512:1024] = ys_b[s][b] = hbuf[1][256-s][b]
__global__ __launch_bounds__(256) void build_encw1(const u16* __restrict__ hbuf,
                                                   u16* __restrict__ ew) {
  int idx = (blockIdx.x * 256 + threadIdx.x) * 8;
  int r = idx >> 10, c = idx & 1023;
  int s = r >> 5, b = r & 31;
  size_t src;
  if (c < 512) src = ((size_t)(s + 1) * 32 + b) * 512 + c;
  else src = ((size_t)(257 + 256 - s) * 32 + b) * 512 + (c - 512);
  *(uint4*)(ew + idx) = *(const uint4*)(hbuf + src);
}

// ssum[r] = sum_t sum_h wv[h]*tanh(b1[r][h] + tp[b][h] + b3[b*16+t][h]) + 16*bv
__global__ __launch_bounds__(256) void scores_k(const float* __restrict__ b1,
                                                const float* __restrict__ tp,
                                                const float* __restrict__ b3,
                                                const float* __restrict__ wv,
                                                const float* __restrict__ bv,
                                                float* __restrict__ ssum) {
  __shared__ float pre[512];
  __shared__ float wvs[512];
  __shared__ float red[4];
  int r = blockIdx.x;
  int tid = threadIdx.x;
  int b = r & 31;
  for (int h = tid; h < 512; h += 256) {
    pre[h] = b1[(size_t)r * 512 + h] + tp[b * 512 + h];
    wvs[h] = wv[h];
  }
  __syncthreads();
  float acc = 0.f;
  for (int t = 0; t < 16; ++t) {
    const float* b3r = b3 + ((size_t)b * 16 + t) * 512;
    for (int h = tid; h < 512; h += 256) acc += wvs[h] * tanhf_(pre[h] + b3r[h]);
  }
  for (int o = 32; o > 0; o >>= 1) acc += __shfl_down(acc, o);
  if ((tid & 63) == 0) red[tid >> 6] = acc;
  __syncthreads();
  if (tid == 0) ssum[r] = red[0] + red[1] + red[2] + red[3] + 16.f * bv[0];
}

// enc_hidden_out[b][n] = sum_k [hT_f|hT_b][b][k] * Who[n][k]
__global__ __launch_bounds__(256) void hidden_k(const u16* __restrict__ hbuf,
                                                const float* __restrict__ Who,
                                                float* __restrict__ outp) {
  int o = blockIdx.x * 256 + threadIdx.x;  // 16384
  int b = o >> 9, n = o & 511;
  const u16* hf = hbuf + ((size_t)256 * 32 + b) * 512;
  const u16* hb = hbuf + ((size_t)(257 + 256) * 32 + b) * 512;
  const float* w = Who + (size_t)n * 1024;
  float acc = 0.f;
  for (int k = 0; k < 512; ++k) acc += bf2f(hf[k]) * w[k];
  for (int k = 0; k < 512; ++k) acc += bf2f(hb[k]) * w[512 + k];
  outp[o] = acc;
}

extern "C" void kernel_launch(void* const* d_in, const int* in_sizes, int n_in,
                              void* d_out, int out_size, void* d_ws, size_t ws_size,
                              hipStream_t stream) {
  (void)in_sizes; (void)n_in; (void)out_size; (void)ws_size;
  const int* theme = (const int*)d_in[0];
  const int* keyword = (const int*)d_in[1];
  const int* src = (const int*)d_in[2];
  const float* theme_tab = (const float*)d_in[3];
  const float* keyword_tab = (const float*)d_in[4];
  const float* src_tab = (const float*)d_in[5];
  const float* Wih_f = (const float*)d_in[6];
  const float* Whh_f = (const float*)d_in[7];
  const float* bih_f = (const float*)d_in[8];
  const float* bhh_f = (const float*)d_in[9];
  const float* Wih_b = (const float*)d_in[10];
  const float* Whh_b = (const float*)d_in[11];
  const float* bih_b = (const float*)d_in[12];
  const float* bhh_b = (const float*)d_in[13];
  const float* Ww = (const float*)d_in[14];
  const float* bw = (const float*)d_in[15];
  const float* Wt = (const float*)d_in[16];
  const float* bt = (const float*)d_in[17];
  const float* Wk = (const float*)d_in[18];
  const float* bk = (const float*)d_in[19];
  const float* wv = (const float*)d_in[20];
  const float* bv = (const float*)d_in[21];
  const float* Wo = (const float*)d_in[22];
  const float* bo = (const float*)d_in[23];
  const float* Who = (const float*)d_in[24];
  float* out = (float*)d_out;
  char* ws = (char*)d_ws;

  u16* gx_cat = (u16*)(ws + OFF_GX);
  u16* hbuf = (u16*)(ws + OFF_HBUF);
  u16* asrc = (u16*)(ws + OFF_ASRC);
  u16* ew1 = (u16*)(ws + OFF_EW1);
  float* b1buf = (float*)(ws + OFF_B1);
  u16* wihc = (u16*)(ws + OFF_WIHC);
  u16* wwb = (u16*)(ws + OFF_WWB);
  u16* wo2b = (u16*)(ws + OFF_WO2B);
  u16* wkb = (u16*)(ws + OFF_WKB);
  u16* kwe = (u16*)(ws + OFF_KWE);
  float* b3buf = (float*)(ws + OFF_B3);
  float* tp = (float*)(ws + OFF_TP);
  float* tpo = (float*)(ws + OFF_TPO);
  float* ssum = (float*)(ws + OFF_SSUM);
  float* biasc = (float*)(ws + OFF_BIASC);
  int* flg = (int*)(ws + OFF_FLG);
  int* clm = (int*)(ws + OFF_CLM);

  // init: flags (526KB, one line per flag) + claim zeroed, h0 = 0 (both dirs)
  hipMemsetAsync(flg, 0, 526336 + 64, stream);
  hipMemsetAsync(hbuf, 0, 32 * 512 * 2, stream);
  hipMemsetAsync(hbuf + (size_t)257 * 32 * 512, 0, 32 * 512 * 2, stream);
  // bias_cat = [bih_f, bih_b]
  hipMemcpyAsync(biasc, bih_f, 1536 * 4, hipMemcpyDeviceToDevice, stream);
  hipMemcpyAsync(biasc + 1536, bih_b, 1536 * 4, hipMemcpyDeviceToDevice, stream);

  // weight conversions
  cvtk<<<768, 256, 0, stream>>>(Wih_f, wihc, 1536 * 512);
  cvtk<<<768, 256, 0, stream>>>(Wih_b, wihc + 1536 * 512, 1536 * 512);
  cvtk<<<512, 256, 0, stream>>>(Ww, wwb, 512 * 1024);
  cvtk<<<256, 256, 0, stream>>>(Wk, wkb, 512 * 512);
  cvt_wo2<<<512, 256, 0, stream>>>(Wo, wo2b);
  // gathers
  gather_rows<<<2048, 256, 0, stream>>>(src, src_tab, asrc, 0);
  gather_rows<<<128, 256, 0, stream>>>(keyword, keyword_tab, kwe, 1);
  // small projections
  proj_tp<<<64, 256, 0, stream>>>(theme, theme_tab, Wt, bt, tp);
  proj_tpo<<<64, 256, 0, stream>>>(tp, Wo, tpo);
  // b3 = kwemb @ Wk^T + bk   (M=512,N=512,K=512)
  gemm_bt<1><<<16, 256, 0, stream>>>(kwe, wkb, bk, b3buf, nullptr, 512, 512, 512,
                                     nullptr, nullptr);
  // gx = src_emb @ [Wih_f;Wih_b]^T + bih  (M=8192,N=3072,K=512) -> bf16
  gemm_bt<0><<<1536, 256, 0, stream>>>(asrc, wihc, biasc, nullptr, gx_cat, 8192,
                                       3072, 512, nullptr, nullptr);
  // sequential bidirectional GRU — one-XCD claim + spread-flag protocol
  gru_scan<<<256, 512, 0, stream>>>(gx_cat, Whh_f, Whh_b, bhh_f, bhh_b, hbuf, flg,
                                    clm);
  // enc_w_1 materialization
  build_encw1<<<4096, 256, 0, stream>>>(hbuf, ew1);
  // b1 = enc_w_1 @ Ww^T + bw  (M=8192,N=512,K=1024) -> f32
  gemm_bt<1><<<256, 256, 0, stream>>>(ew1, wwb, bw, b1buf, nullptr, 8192, 512, 1024,
                                      nullptr, nullptr);
  // attention scalar per (s,b)
  scores_k<<<8192, 256, 0, stream>>>(b1buf, tp, b3buf, wv, bv, ssum);
  // enc_out = enc_w1 @ Wo2^T + bo + ssum*tpo  -> d_out (f32)
  gemm_bt<2><<<256, 256, 0, stream>>>(ew1, wo2b, bo, out, nullptr, 8192, 512, 1024,
                                      ssum, tpo);
  // enc_hidden_out
  hidden_k<<<64, 256, 0, stream>>>(hbuf, Who, out + 4194304);
}